// Round 1
// baseline (2050.983 us; speedup 1.0000x reference)
//
#include <hip/hip_runtime.h>

#define NN 100000      // N_NODES
#define NE 3200000     // N_EDGES
#define NF 128         // N_F
#define NH 128         // HIDDEN
#define NP 8           // N_PRED
#define NG 64          // N_GRAPHS

// ---------------- init: deg=1 (self-loop), cnt=0, psum=0 ----------------
__global__ void k_init(float* __restrict__ deg, float* __restrict__ cnt,
                       float* __restrict__ psum) {
    int i = blockIdx.x * blockDim.x + threadIdx.x;
    if (i < NN) deg[i] = 1.0f;
    if (i < NG) cnt[i] = 0.0f;
    if (i < NG * NH) psum[i] = 0.0f;
}

// ---------------- deg[col[e]] += w[e] ----------------
__global__ void k_deg(const int* __restrict__ ei, const float* __restrict__ w,
                      float* __restrict__ deg) {
    int e = blockIdx.x * blockDim.x + threadIdx.x;
    if (e >= NE) return;
    atomicAdd(&deg[ei[NE + e]], w[e]);
}

// ---------------- per-graph node counts ----------------
__global__ void k_cnt(const int* __restrict__ batch, float* __restrict__ cnt) {
    __shared__ float c[NG];
    int t = threadIdx.x;
    if (t < NG) c[t] = 0.0f;
    __syncthreads();
    int i = blockIdx.x * blockDim.x + t;
    if (i < NN) atomicAdd(&c[batch[i]], 1.0f);
    __syncthreads();
    if (t < NG && c[t] != 0.0f) atomicAdd(&cnt[t], c[t]);
}

// ---------------- deg -> dinv (in place) ----------------
__global__ void k_dinv(float* __restrict__ deg) {
    int i = blockIdx.x * blockDim.x + threadIdx.x;
    if (i >= NN) return;
    float d = deg[i];
    deg[i] = d > 0.0f ? rsqrtf(d) : 0.0f;
}

// ---------------- norm[e] = dinv[row]*w*dinv[col] ----------------
__global__ void k_norm(const int* __restrict__ ei, const float* __restrict__ w,
                       const float* __restrict__ dinv, float* __restrict__ nrm) {
    int e = blockIdx.x * blockDim.x + threadIdx.x;
    if (e >= NE) return;
    int r = ei[e], c = ei[NE + e];
    nrm[e] = dinv[r] * w[e] * dinv[c];
}

// ---------------- hop 1 fused with one-hot P ----------------
// Q1[n][g] = dinv[n]^2 * (batch[n]==g)   (self-loop part)
__global__ void k_q1_init(const int* __restrict__ batch,
                          const float* __restrict__ dinv, float* __restrict__ Q) {
    int i = blockIdx.x * blockDim.x + threadIdx.x;
    if (i >= NN * NG) return;
    int n = i >> 6, g = i & 63;
    float d = dinv[n];
    Q[i] = (batch[n] == g) ? d * d : 0.0f;
}

// Q1[row[e]][batch[col[e]]] += norm[e]   (one atomic per edge)
__global__ void k_q1_scatter(const int* __restrict__ ei, const int* __restrict__ batch,
                             const float* __restrict__ nrm, float* __restrict__ Q) {
    int e = blockIdx.x * blockDim.x + threadIdx.x;
    if (e >= NE) return;
    int r = ei[e], c = ei[NE + e];
    atomicAdd(&Q[(r << 6) + batch[c]], nrm[e]);
}

// ---------------- hops 2,3: self-loop init ----------------
// Qout[n][:] = dinv[n]^2 * Qin[n][:]
__global__ void k_hop_init(const float* __restrict__ dinv,
                           const float* __restrict__ Qin, float* __restrict__ Qout) {
    int i = blockIdx.x * blockDim.x + threadIdx.x;
    if (i >= NN * NG) return;
    int n = i >> 6;
    float d = dinv[n];
    Qout[i] = d * d * Qin[i];
}

// Qout[row[e]][lane] += norm[e] * Qin[col[e]][lane]   (wave per edge)
__global__ void k_hop_scatter(const int* __restrict__ ei, const float* __restrict__ nrm,
                              const float* __restrict__ Qin, float* __restrict__ Qout) {
    int idx = blockIdx.x * blockDim.x + threadIdx.x;
    int e = idx >> 6;
    if (e >= NE) return;
    int lane = idx & 63;
    int r = ei[e], c = ei[NE + e];
    atomicAdd(&Qout[(r << 6) + lane], nrm[e] * Qin[(c << 6) + lane]);
}

// ---------------- psum[g][f] = sum_n Q3[n][g] * x[n][f] ----------------
__global__ __launch_bounds__(256) void k_pool(const float* __restrict__ Q,
                                              const float* __restrict__ x,
                                              float* __restrict__ psum) {
    __shared__ float q[NG];
    __shared__ float xv[NF];
    int t = threadIdx.x;
    int f0 = t & 31;   // 0..31
    int g8 = t >> 5;   // 0..7
    float acc[8][4] = {};
    for (int n = blockIdx.x; n < NN; n += gridDim.x) {
        if (t < 64) q[t] = Q[n * 64 + t];
        else if (t < 192) xv[t - 64] = x[n * 128 + (t - 64)];
        __syncthreads();
#pragma unroll
        for (int i = 0; i < 8; ++i) {
            float qv = q[g8 * 8 + i];
#pragma unroll
            for (int j = 0; j < 4; ++j)
                acc[i][j] += qv * xv[f0 + 32 * j];
        }
        __syncthreads();
    }
#pragma unroll
    for (int i = 0; i < 8; ++i)
#pragma unroll
        for (int j = 0; j < 4; ++j)
            atomicAdd(&psum[(g8 * 8 + i) * NF + f0 + 32 * j], acc[i][j]);
}

// ---------------- final: fold both linears ----------------
__global__ void k_final(const float* __restrict__ psum, const float* __restrict__ cnt,
                        const float* __restrict__ Wc, const float* __restrict__ bc,
                        const float* __restrict__ Wl, const float* __restrict__ bl,
                        float* __restrict__ out) {
    __shared__ float M[NP * NH];   // M[p][f] = sum_h Wl[p][h]*Wc[h][f]
    __shared__ float bias[NP];
    int t = threadIdx.x;   // 256 threads
    for (int idx = t; idx < NP * NH; idx += 256) {
        int p = idx >> 7, f = idx & 127;
        float s = 0.0f;
        for (int h = 0; h < NH; ++h) s += Wl[p * NH + h] * Wc[h * NF + f];
        M[idx] = s;
    }
    if (t < NP) {
        float s = bl[t];
        for (int h = 0; h < NH; ++h) s += Wl[t * NH + h] * bc[h];
        bias[t] = s;
    }
    __syncthreads();
    for (int idx = t; idx < NG * NP; idx += 256) {
        int g = idx >> 3, p = idx & 7;
        float inv = 1.0f / fmaxf(cnt[g], 1.0f);
        float s = 0.0f;
        for (int f = 0; f < NF; ++f) s += psum[g * NF + f] * M[p * NH + f];
        out[idx] = s * inv + bias[p];
    }
}

extern "C" void kernel_launch(void* const* d_in, const int* in_sizes, int n_in,
                              void* d_out, int out_size, void* d_ws, size_t ws_size,
                              hipStream_t stream) {
    const float* x     = (const float*)d_in[0];
    const int*   ei    = (const int*)d_in[1];
    const float* ea    = (const float*)d_in[2];
    const int*   batch = (const int*)d_in[3];
    const float* Wc    = (const float*)d_in[4];
    const float* bc    = (const float*)d_in[5];
    const float* Wl    = (const float*)d_in[6];
    const float* bl    = (const float*)d_in[7];
    float* out = (float*)d_out;

    float* ws   = (float*)d_ws;
    float* deg  = ws;                 // N floats (becomes dinv in place)
    float* nrm  = deg + NN;           // E floats
    float* Qa   = nrm + NE;           // N*64
    float* Qb   = Qa + (size_t)NN * NG; // N*64
    float* cnt  = Qb + (size_t)NN * NG; // 64
    float* psum = cnt + NG;           // 64*128

    const int B = 256;
    int gN  = (NN + B - 1) / B;          // 391
    int gE  = (NE + B - 1) / B;          // 12500
    int gNQ = (NN * NG + B - 1) / B;     // 25000
    int gEQ = (int)(((long long)NE * 64 + B - 1) / B);  // 800000

    k_init<<<gN, B, 0, stream>>>(deg, cnt, psum);
    k_deg<<<gE, B, 0, stream>>>(ei, ea, deg);
    k_cnt<<<gN, B, 0, stream>>>(batch, cnt);
    k_dinv<<<gN, B, 0, stream>>>(deg);
    k_norm<<<gE, B, 0, stream>>>(ei, ea, deg, nrm);

    // hop 1 (fused one-hot): Qa = A^T P + selfloops
    k_q1_init<<<gNQ, B, 0, stream>>>(batch, deg, Qa);
    k_q1_scatter<<<gE, B, 0, stream>>>(ei, batch, nrm, Qa);

    // hop 2: Qb = A^T Qa
    k_hop_init<<<gNQ, B, 0, stream>>>(deg, Qa, Qb);
    k_hop_scatter<<<gEQ, B, 0, stream>>>(ei, nrm, Qa, Qb);

    // hop 3: Qa = A^T Qb
    k_hop_init<<<gNQ, B, 0, stream>>>(deg, Qb, Qa);
    k_hop_scatter<<<gEQ, B, 0, stream>>>(ei, nrm, Qb, Qa);

    // pooled sums and final fold
    k_pool<<<256, B, 0, stream>>>(Qa, x, psum);
    k_final<<<1, B, 0, stream>>>(psum, cnt, Wc, bc, Wl, bl, out);
}

// Round 2
// 1131.748 us; speedup vs baseline: 1.8122x; 1.8122x over previous
//
#include <hip/hip_runtime.h>

#define NN 100000      // N_NODES
#define NE 3200000     // N_EDGES
#define NF 128         // N_F
#define NH 128         // HIDDEN
#define NP 8           // N_PRED
#define NG 64          // N_GRAPHS

#define SCAN_B 1024
#define SCAN_NBLK 98   // ceil(100000/1024) -> 98*1024 = 100352

// ---------------- init: deg=1 (self-loop), rcnt=0, cnt=0, psum=0 ----------------
__global__ void k_init(float* __restrict__ deg, int* __restrict__ rcnt,
                       float* __restrict__ cnt, float* __restrict__ psum) {
    int i = blockIdx.x * blockDim.x + threadIdx.x;
    if (i < NN) { deg[i] = 1.0f; rcnt[i] = 0; }
    if (i < NG) cnt[i] = 0.0f;
    if (i < NG * NH) psum[i] = 0.0f;
}

// ---------------- deg[col[e]] += w[e]  and  rcnt[row[e]]++ ----------------
__global__ void k_deg_count(const int* __restrict__ ei, const float* __restrict__ w,
                            float* __restrict__ deg, int* __restrict__ rcnt) {
    int e = blockIdx.x * blockDim.x + threadIdx.x;
    if (e >= NE) return;
    atomicAdd(&deg[ei[NE + e]], w[e]);
    atomicAdd(&rcnt[ei[e]], 1);
}

// ---------------- per-graph node counts ----------------
__global__ void k_cnt(const int* __restrict__ batch, float* __restrict__ cnt) {
    __shared__ float c[NG];
    int t = threadIdx.x;
    if (t < NG) c[t] = 0.0f;
    __syncthreads();
    int i = blockIdx.x * blockDim.x + t;
    if (i < NN) atomicAdd(&c[batch[i]], 1.0f);
    __syncthreads();
    if (t < NG && c[t] != 0.0f) atomicAdd(&cnt[t], c[t]);
}

// ---------------- deg -> dinv (in place) ----------------
__global__ void k_dinv(float* __restrict__ deg) {
    int i = blockIdx.x * blockDim.x + threadIdx.x;
    if (i >= NN) return;
    float d = deg[i];
    deg[i] = d > 0.0f ? rsqrtf(d) : 0.0f;
}

// ---------------- scan pass 1: per-block exclusive prefix + block sums ----------------
__global__ __launch_bounds__(SCAN_B) void k_scan1(const int* __restrict__ rcnt,
                                                  int* __restrict__ px,
                                                  int* __restrict__ bsum) {
    __shared__ int s[SCAN_B];
    int t = threadIdx.x;
    int i = blockIdx.x * SCAN_B + t;
    int v = (i < NN) ? rcnt[i] : 0;
    s[t] = v;
    __syncthreads();
    for (int off = 1; off < SCAN_B; off <<= 1) {
        int x = (t >= off) ? s[t - off] : 0;
        __syncthreads();
        s[t] += x;
        __syncthreads();
    }
    px[i] = s[t] - v;   // exclusive within block
    if (t == SCAN_B - 1) bsum[blockIdx.x] = s[t];
}

// ---------------- scan pass 2: exclusive scan of 98 block sums ----------------
__global__ void k_scan2(const int* __restrict__ bsum, int* __restrict__ bofs) {
    if (threadIdx.x == 0) {
        int acc = 0;
        for (int b = 0; b < SCAN_NBLK; ++b) { bofs[b] = acc; acc += bsum[b]; }
    }
}

// ---------------- scan pass 3: rowptr[i] = px[i] + bofs[blk]; rpos = rowptr ----------------
__global__ void k_scan3(const int* __restrict__ px, const int* __restrict__ bofs,
                        int* __restrict__ rowptr, int* __restrict__ rpos) {
    int i = blockIdx.x * blockDim.x + threadIdx.x;
    if (i > NN) return;
    int v = px[i] + bofs[i >> 10];
    rowptr[i] = v;
    if (i < NN) rpos[i] = v;
}

// ---------------- fill CSR: pack[pos] = (src, norm) sorted by dest row ----------------
__global__ void k_fill(const int* __restrict__ ei, const float* __restrict__ w,
                       const float* __restrict__ dinv, int* __restrict__ rpos,
                       float2* __restrict__ pack) {
    int e = blockIdx.x * blockDim.x + threadIdx.x;
    if (e >= NE) return;
    int r = ei[e], c = ei[NE + e];
    float n = dinv[r] * w[e] * dinv[c];
    int p = atomicAdd(&rpos[r], 1);
    pack[p] = make_float2(__int_as_float(c), n);
}

// ---------------- hop 1: Qa[n][g] = dinv^2*(batch[n]==g) + sum nrm*(batch[src]==g) ----------------
__global__ void k_q1_gather(const int* __restrict__ rowptr, const float2* __restrict__ pack,
                            const int* __restrict__ batch, const float* __restrict__ dinv,
                            float* __restrict__ Q) {
    int wid = (blockIdx.x * blockDim.x + threadIdx.x) >> 6;
    int lane = threadIdx.x & 63;
    if (wid >= NN) return;
    int beg = rowptr[wid], end = rowptr[wid + 1];
    float d = dinv[wid];
    float acc = (batch[wid] == lane) ? d * d : 0.0f;
    int e = beg;
    for (; e + 4 <= end; e += 4) {
        float2 p0 = pack[e], p1 = pack[e + 1], p2 = pack[e + 2], p3 = pack[e + 3];
        int b0 = batch[__float_as_int(p0.x)];
        int b1 = batch[__float_as_int(p1.x)];
        int b2 = batch[__float_as_int(p2.x)];
        int b3 = batch[__float_as_int(p3.x)];
        acc += (b0 == lane ? p0.y : 0.0f) + (b1 == lane ? p1.y : 0.0f)
             + (b2 == lane ? p2.y : 0.0f) + (b3 == lane ? p3.y : 0.0f);
    }
    for (; e < end; ++e) {
        float2 p = pack[e];
        acc += (batch[__float_as_int(p.x)] == lane) ? p.y : 0.0f;
    }
    Q[(wid << 6) + lane] = acc;
}

// ---------------- hops 2,3: Qout[n][g] = dinv^2*Qin[n][g] + sum nrm*Qin[src][g] ----------------
__global__ void k_hop_gather(const int* __restrict__ rowptr, const float2* __restrict__ pack,
                             const float* __restrict__ dinv, const float* __restrict__ Qin,
                             float* __restrict__ Qout) {
    int wid = (blockIdx.x * blockDim.x + threadIdx.x) >> 6;
    int lane = threadIdx.x & 63;
    if (wid >= NN) return;
    int beg = rowptr[wid], end = rowptr[wid + 1];
    float d = dinv[wid];
    float acc = d * d * Qin[(wid << 6) + lane];
    int e = beg;
    for (; e + 4 <= end; e += 4) {
        float2 p0 = pack[e], p1 = pack[e + 1], p2 = pack[e + 2], p3 = pack[e + 3];
        float q0 = Qin[(__float_as_int(p0.x) << 6) + lane];
        float q1 = Qin[(__float_as_int(p1.x) << 6) + lane];
        float q2 = Qin[(__float_as_int(p2.x) << 6) + lane];
        float q3 = Qin[(__float_as_int(p3.x) << 6) + lane];
        acc += p0.y * q0 + p1.y * q1 + p2.y * q2 + p3.y * q3;
    }
    for (; e < end; ++e) {
        float2 p = pack[e];
        acc += p.y * Qin[(__float_as_int(p.x) << 6) + lane];
    }
    Qout[(wid << 6) + lane] = acc;
}

// ---------------- psum[g][f] = sum_n Q3[n][g] * x[n][f] ----------------
__global__ __launch_bounds__(256) void k_pool(const float* __restrict__ Q,
                                              const float* __restrict__ x,
                                              float* __restrict__ psum) {
    __shared__ float q[NG];
    __shared__ float xv[NF];
    int t = threadIdx.x;
    int f0 = t & 31;
    int g8 = t >> 5;
    float acc[8][4] = {};
    for (int n = blockIdx.x; n < NN; n += gridDim.x) {
        if (t < 64) q[t] = Q[n * 64 + t];
        else if (t < 192) xv[t - 64] = x[n * 128 + (t - 64)];
        __syncthreads();
#pragma unroll
        for (int i = 0; i < 8; ++i) {
            float qv = q[g8 * 8 + i];
#pragma unroll
            for (int j = 0; j < 4; ++j)
                acc[i][j] += qv * xv[f0 + 32 * j];
        }
        __syncthreads();
    }
#pragma unroll
    for (int i = 0; i < 8; ++i)
#pragma unroll
        for (int j = 0; j < 4; ++j)
            atomicAdd(&psum[(g8 * 8 + i) * NF + f0 + 32 * j], acc[i][j]);
}

// ---------------- final: fold both linears ----------------
__global__ void k_final(const float* __restrict__ psum, const float* __restrict__ cnt,
                        const float* __restrict__ Wc, const float* __restrict__ bc,
                        const float* __restrict__ Wl, const float* __restrict__ bl,
                        float* __restrict__ out) {
    __shared__ float M[NP * NH];
    __shared__ float bias[NP];
    int t = threadIdx.x;
    for (int idx = t; idx < NP * NH; idx += 256) {
        int p = idx >> 7, f = idx & 127;
        float s = 0.0f;
        for (int h = 0; h < NH; ++h) s += Wl[p * NH + h] * Wc[h * NF + f];
        M[idx] = s;
    }
    if (t < NP) {
        float s = bl[t];
        for (int h = 0; h < NH; ++h) s += Wl[t * NH + h] * bc[h];
        bias[t] = s;
    }
    __syncthreads();
    for (int idx = t; idx < NG * NP; idx += 256) {
        int g = idx >> 3, p = idx & 7;
        float inv = 1.0f / fmaxf(cnt[g], 1.0f);
        float s = 0.0f;
        for (int f = 0; f < NF; ++f) s += psum[g * NF + f] * M[p * NH + f];
        out[idx] = s * inv + bias[p];
    }
}

extern "C" void kernel_launch(void* const* d_in, const int* in_sizes, int n_in,
                              void* d_out, int out_size, void* d_ws, size_t ws_size,
                              hipStream_t stream) {
    const float* x     = (const float*)d_in[0];
    const int*   ei    = (const int*)d_in[1];
    const float* ea    = (const float*)d_in[2];
    const int*   batch = (const int*)d_in[3];
    const float* Wc    = (const float*)d_in[4];
    const float* bc    = (const float*)d_in[5];
    const float* Wl    = (const float*)d_in[6];
    const float* bl    = (const float*)d_in[7];
    float* out = (float*)d_out;

    // workspace layout (floats unless noted)
    float* ws     = (float*)d_ws;
    float* deg    = ws;                           // NN (becomes dinv)
    float* Qa     = deg + NN;                     // NN*64
    float* Qb     = Qa + (size_t)NN * NG;         // NN*64
    float* cnt    = Qb + (size_t)NN * NG;         // NG
    float* psum   = cnt + NG;                     // NG*NH
    int*   rcnt   = (int*)(psum + NG * NH);       // NN
    int*   px     = rcnt + NN;                    // SCAN_NBLK*SCAN_B
    int*   bsum   = px + SCAN_NBLK * SCAN_B;      // SCAN_NBLK
    int*   bofs   = bsum + SCAN_NBLK;             // SCAN_NBLK
    int*   rowptr = bofs + SCAN_NBLK;             // NN+1
    int*   rpos   = rowptr + (NN + 1);            // NN
    float2* pack  = (float2*)(rpos + NN);         // NE float2

    const int B = 256;
    int gN  = (NN + B - 1) / B;                          // 391
    int gE  = (NE + B - 1) / B;                          // 12500
    int gW  = (int)(((long long)NN * 64 + B - 1) / B);   // 25000 (wave per node)

    k_init<<<gN, B, 0, stream>>>(deg, rcnt, cnt, psum);
    k_deg_count<<<gE, B, 0, stream>>>(ei, ea, deg, rcnt);
    k_cnt<<<gN, B, 0, stream>>>(batch, cnt);
    k_dinv<<<gN, B, 0, stream>>>(deg);

    // CSR build: scan rcnt -> rowptr, then fill (src,norm) packed pairs
    k_scan1<<<SCAN_NBLK, SCAN_B, 0, stream>>>(rcnt, px, bsum);
    k_scan2<<<1, 64, 0, stream>>>(bsum, bofs);
    k_scan3<<<(NN + 1 + SCAN_B - 1) / SCAN_B, SCAN_B, 0, stream>>>(px, bofs, rowptr, rpos);
    k_fill<<<gE, B, 0, stream>>>(ei, ea, deg, rpos, pack);

    // 3 propagation hops, all gather-based (no atomics)
    k_q1_gather<<<gW, B, 0, stream>>>(rowptr, pack, batch, deg, Qa);
    k_hop_gather<<<gW, B, 0, stream>>>(rowptr, pack, deg, Qa, Qb);
    k_hop_gather<<<gW, B, 0, stream>>>(rowptr, pack, deg, Qb, Qa);

    // pooled sums and final fold
    k_pool<<<256, B, 0, stream>>>(Qa, x, psum);
    k_final<<<1, B, 0, stream>>>(psum, cnt, Wc, bc, Wl, bl, out);
}